// Round 1
// baseline (391.926 us; speedup 1.0000x reference)
//
#include <hip/hip_runtime.h>

#define E_TOTAL 32768
#define F_IN 17
#define HID 64
#define NJ 768

using bf16x8 = __attribute__((ext_vector_type(8))) short;
using f32x4  = __attribute__((ext_vector_type(4))) float;

__device__ __forceinline__ unsigned short f2bf(float x){
    unsigned u = __float_as_uint(x);
    u += 0x7fffu + ((u >> 16) & 1u);          // round-to-nearest-even
    return (unsigned short)(u >> 16);
}

// ---------------- Kernel 0: W3 (64x768 f32) -> W3T (768x64 bf16) ----------------
__global__ __launch_bounds__(256) void prep_w3(const float* __restrict__ W3,
                                               unsigned short* __restrict__ w3t){
    int t = blockIdx.x * 256 + threadIdx.x;   // 0..49151 ; t = n*64 + k
    int n = t >> 6, k = t & 63;
    w3t[t] = f2bf(W3[k * NJ + n]);
}

// ---------------- Kernel A: radial MLP, one wave per 4 edges ----------------
__global__ __launch_bounds__(256) void mlp_kernel(const float* __restrict__ feat,
        const float* __restrict__ W1, const float* __restrict__ b1, const float* __restrict__ g1,
        const float* __restrict__ W2, const float* __restrict__ b2, const float* __restrict__ g2,
        unsigned short* __restrict__ hb){
    __shared__ float sW1[F_IN * HID];
    __shared__ float sW2[HID * HID];
    __shared__ float sC[4 * HID];            // b1 | g1 | b2 | g2
    __shared__ float sFeat[16 * F_IN];
    __shared__ __align__(16) float sH1[16][HID];

    int tid = threadIdx.x;
    int e0  = blockIdx.x * 16;
    for (int i = tid; i < F_IN * HID; i += 256) sW1[i] = W1[i];
    for (int i = tid; i < HID * HID; i += 256) sW2[i] = W2[i];
    if (tid < 64) { sC[tid] = b1[tid]; sC[64 + tid] = g1[tid];
                    sC[128 + tid] = b2[tid]; sC[192 + tid] = g2[tid]; }
    for (int i = tid; i < 16 * F_IN; i += 256) sFeat[i] = feat[(size_t)e0 * F_IN + i];
    __syncthreads();

    int j = tid & 63, wv = tid >> 6;          // wave wv owns edges wv*4 .. wv*4+3
    float acc[4], x[4], s1[4], s2[4];

    // ---- layer 1: 17 -> 64 ----
    #pragma unroll
    for (int q = 0; q < 4; ++q) acc[q] = sC[j];
    for (int k = 0; k < F_IN; ++k){
        float w = sW1[k * 64 + j];
        #pragma unroll
        for (int q = 0; q < 4; ++q) acc[q] += sFeat[(wv * 4 + q) * F_IN + k] * w;
    }
    #pragma unroll
    for (int q = 0; q < 4; ++q){
        float a = acc[q];
        float sg = 1.0f / (1.0f + __expf(-a));
        x[q] = a * sg; s1[q] = x[q]; s2[q] = x[q] * x[q];
    }
    #pragma unroll
    for (int m = 1; m < 64; m <<= 1){
        #pragma unroll
        for (int q = 0; q < 4; ++q){
            s1[q] += __shfl_xor(s1[q], m);
            s2[q] += __shfl_xor(s2[q], m);
        }
    }
    #pragma unroll
    for (int q = 0; q < 4; ++q){
        float mu  = s1[q] * (1.0f / 64.0f);
        float var = s2[q] * (1.0f / 64.0f) - mu * mu;
        float rs  = rsqrtf(var + 1e-5f);
        sH1[wv * 4 + q][j] = (x[q] - mu) * rs * sC[64 + j];
    }
    // wave-local LDS write->read; LDS ops from one wave are ordered, no barrier needed

    // ---- layer 2: 64 -> 64 ----
    #pragma unroll
    for (int q = 0; q < 4; ++q) acc[q] = sC[128 + j];
    for (int k4 = 0; k4 < 16; ++k4){
        float hv[4][4];
        #pragma unroll
        for (int q = 0; q < 4; ++q) *(float4*)hv[q] = *(const float4*)&sH1[wv * 4 + q][k4 * 4];
        #pragma unroll
        for (int kk = 0; kk < 4; ++kk){
            float w = sW2[(k4 * 4 + kk) * 64 + j];
            #pragma unroll
            for (int q = 0; q < 4; ++q) acc[q] += hv[q][kk] * w;
        }
    }
    #pragma unroll
    for (int q = 0; q < 4; ++q){
        float a = acc[q];
        float sg = 1.0f / (1.0f + __expf(-a));
        x[q] = a * sg; s1[q] = x[q]; s2[q] = x[q] * x[q];
    }
    #pragma unroll
    for (int m = 1; m < 64; m <<= 1){
        #pragma unroll
        for (int q = 0; q < 4; ++q){
            s1[q] += __shfl_xor(s1[q], m);
            s2[q] += __shfl_xor(s2[q], m);
        }
    }
    #pragma unroll
    for (int q = 0; q < 4; ++q){
        float mu  = s1[q] * (1.0f / 64.0f);
        float var = s2[q] * (1.0f / 64.0f) - mu * mu;
        float rs  = rsqrtf(var + 1e-5f);
        float h2  = (x[q] - mu) * rs * sC[192 + j];
        hb[(size_t)(e0 + wv * 4 + q) * 64 + j] = f2bf(h2);
    }
}

// ---------------- Kernel B: R = h@W3 + b3 (MFMA) fused with einsum + write ----------------
__global__ __launch_bounds__(256) void tp_kernel(const unsigned short* __restrict__ hb,
        const unsigned short* __restrict__ w3t, const float* __restrict__ b3,
        const float* __restrict__ basis, float* __restrict__ out){
    __shared__ __align__(16) unsigned short sA[16 * 72];   // 16 edges x 64 k, row stride 72 (pad)
    __shared__ float sB3[NJ];
    __shared__ float sBasis[16 * 27];
    __shared__ float sR[16 * 776];                          // 768 + 8 pad

    int tid = threadIdx.x;
    int bid = blockIdx.x;
    int e0  = bid * 16;

    // stage h tile (1024 bf16 = 512 dwords), insert row padding
    for (int idx = tid; idx < 512; idx += 256){
        int e = idx >> 5, c = idx & 31;
        unsigned v = ((const unsigned*)(hb + (size_t)e0 * 64))[idx];
        *((unsigned*)(sA + e * 72 + c * 2)) = v;
    }
    for (int idx = tid; idx < NJ; idx += 256) sB3[idx] = b3[idx];
    for (int idx = tid; idx < 16 * 27; idx += 256) sBasis[idx] = basis[(size_t)e0 * 27 + idx];
    __syncthreads();

    int wv = tid >> 6, l = tid & 63;
    int col = l & 15, kg = l >> 4;

    // ---- phase 1: MFMA GEMM, wave wv covers cols [wv*192, wv*192+192) ----
    bf16x8 a0 = *(const bf16x8*)(sA + (l & 15) * 72 + kg * 8);        // A[e][k0..k0+7], k in [0,32)
    bf16x8 a1 = *(const bf16x8*)(sA + (l & 15) * 72 + 32 + kg * 8);   // k in [32,64)
    #pragma unroll 3
    for (int t = 0; t < 12; ++t){
        int n0 = wv * 192 + t * 16;
        bf16x8 bb0 = *(const bf16x8*)(w3t + (size_t)(n0 + col) * 64 + kg * 8);
        bf16x8 bb1 = *(const bf16x8*)(w3t + (size_t)(n0 + col) * 64 + 32 + kg * 8);
        f32x4 acc = {0.f, 0.f, 0.f, 0.f};
        acc = __builtin_amdgcn_mfma_f32_16x16x32_bf16(a0, bb0, acc, 0, 0, 0);
        acc = __builtin_amdgcn_mfma_f32_16x16x32_bf16(a1, bb1, acc, 0, 0, 0);
        float bj = sB3[n0 + col];
        #pragma unroll
        for (int r = 0; r < 4; ++r){
            int e = kg * 4 + r;                // D row = (lane>>4)*4 + reg
            sR[e * 776 + n0 + col] = acc[r] + bj;
        }
    }
    __syncthreads();

    // ---- phase 2: einsum + coalesced-ish write ----
    int g = l >> 4, s = l & 15;
    int e_loc = wv * 4 + g;
    float bs[27];
    #pragma unroll
    for (int z = 0; z < 27; ++z) bs[z] = sBasis[e_loc * 27 + z];
    float* outE = out + (size_t)(e0 + e_loc) * 2304;
    const float* Rrow = sR + e_loc * 776;

    #pragma unroll 4
    for (int task = 0; task < 16; ++task){      // task = o, s = i
        int oi = task * 16 + s;
        float r0 = Rrow[oi * 3 + 0];
        float r1 = Rrow[oi * 3 + 1];
        float r2 = Rrow[oi * 3 + 2];
        #pragma unroll
        for (int d = 0; d < 3; ++d){
            float* p = outE + task * 144 + d * 48 + s * 3;
            #pragma unroll
            for (int m = 0; m < 3; ++m){
                int z = d * 9 + m * 3;
                p[m] = r0 * bs[z + 0] + r1 * bs[z + 1] + r2 * bs[z + 2];
            }
        }
    }
}

extern "C" void kernel_launch(void* const* d_in, const int* in_sizes, int n_in,
                              void* d_out, int out_size, void* d_ws, size_t ws_size,
                              hipStream_t stream) {
    const float* feat  = (const float*)d_in[0];
    const float* basis = (const float*)d_in[1];
    const float* W1 = (const float*)d_in[2];
    const float* b1 = (const float*)d_in[3];
    const float* g1 = (const float*)d_in[4];
    const float* W2 = (const float*)d_in[5];
    const float* b2 = (const float*)d_in[6];
    const float* g2 = (const float*)d_in[7];
    const float* W3 = (const float*)d_in[8];
    const float* b3 = (const float*)d_in[9];
    float* out = (float*)d_out;

    unsigned short* hbuf = (unsigned short*)d_ws;                       // 32768*64*2 = 4 MB
    unsigned short* w3t  = hbuf + (size_t)E_TOTAL * HID;                // 768*64*2 = 96 KB

    prep_w3<<<NJ * HID / 256, 256, 0, stream>>>(W3, w3t);
    mlp_kernel<<<E_TOTAL / 16, 256, 0, stream>>>(feat, W1, b1, g1, W2, b2, g2, hbuf);
    tp_kernel<<<E_TOTAL / 16, 256, 0, stream>>>(hbuf, w3t, b3, basis, out);
}